// Round 4
// baseline (308.856 us; speedup 1.0000x reference)
//
#include <hip/hip_runtime.h>
#include <math.h>

#define BB 512
#define NN 512
#define DD 128
#define S_CHUNKS 4
#define CHUNK (NN / S_CHUNKS)     // 128 rows per chunk
#define PSTRIDE 132               // floats per partial slot: 128 s + 1 t, padded

// Fused kernel: grid = BB*S_CHUNKS blocks of 256 threads.
// Phase 1 (all blocks): partial weighted sum for (b, chunk):
//   s[b,d] = sum_{n in chunk, n < ns[b]} sigmoid(h[b,n]*W_g + b_g) * h[b,n,d]
// Phase 2 (last-arriving block per b, via device-scope atomic counter):
//   hG[e] = W_f[e,:] . s[b,:] + t[b]*b_f[e];  out = hG / max(||hG||, eps)
// Single compute node: removes the k1-drain -> k2-ramp serialization.
__global__ __launch_bounds__(256) void k_fused(
    const float* __restrict__ h,
    const int*   __restrict__ ns,
    const float* __restrict__ W_g,
    const float* __restrict__ b_g,
    const float* __restrict__ W_f,
    const float* __restrict__ b_f,
    float*       __restrict__ part,
    int*         __restrict__ cnt,
    float*       __restrict__ out)
{
    const int bc   = blockIdx.x;
    const int b    = bc / S_CHUNKS;
    const int c    = bc % S_CHUNKS;
    const int tid  = threadIdx.x;
    const int grp  = tid >> 5;
    const int lane = tid & 31;

    const int nsb   = ns[b];
    const int start = c * CHUNK;
    const int end   = min(start + CHUNK, nsb);

    __shared__ float lds_s[8 * 128];
    __shared__ float lds_t[8];
    __shared__ float red[2];
    __shared__ int   is_last;

    const float4 wg = ((const float4*)W_g)[lane];
    const float  bg = b_g[0];
    const float4* hb = (const float4*)(h + (size_t)b * NN * DD);  // row r -> hb[r*32+lane]

    float4 acc  = make_float4(0.f, 0.f, 0.f, 0.f);
    float  tacc = 0.f;

    int n = start + grp;
    for (; n + 24 < end; n += 32) {          // 4 rows in flight per group
        const float4 v0 = hb[(size_t)(n     ) * 32 + lane];
        const float4 v1 = hb[(size_t)(n +  8) * 32 + lane];
        const float4 v2 = hb[(size_t)(n + 16) * 32 + lane];
        const float4 v3 = hb[(size_t)(n + 24) * 32 + lane];

        float d0 = v0.x * wg.x + v0.y * wg.y + v0.z * wg.z + v0.w * wg.w;
        float d1 = v1.x * wg.x + v1.y * wg.y + v1.z * wg.z + v1.w * wg.w;
        float d2 = v2.x * wg.x + v2.y * wg.y + v2.z * wg.z + v2.w * wg.w;
        float d3 = v3.x * wg.x + v3.y * wg.y + v3.z * wg.z + v3.w * wg.w;
        #pragma unroll
        for (int m = 1; m <= 16; m <<= 1) {
            d0 += __shfl_xor(d0, m);
            d1 += __shfl_xor(d1, m);
            d2 += __shfl_xor(d2, m);
            d3 += __shfl_xor(d3, m);
        }
        const float g0 = 1.f / (1.f + expf(-(d0 + bg)));
        const float g1 = 1.f / (1.f + expf(-(d1 + bg)));
        const float g2 = 1.f / (1.f + expf(-(d2 + bg)));
        const float g3 = 1.f / (1.f + expf(-(d3 + bg)));

        acc.x += g0 * v0.x + g1 * v1.x + g2 * v2.x + g3 * v3.x;
        acc.y += g0 * v0.y + g1 * v1.y + g2 * v2.y + g3 * v3.y;
        acc.z += g0 * v0.z + g1 * v1.z + g2 * v2.z + g3 * v3.z;
        acc.w += g0 * v0.w + g1 * v1.w + g2 * v2.w + g3 * v3.w;
        tacc  += g0 + g1 + g2 + g3;
    }
    for (; n < end; n += 8) {                // remainder rows
        const float4 v = hb[(size_t)n * 32 + lane];
        float d = v.x * wg.x + v.y * wg.y + v.z * wg.z + v.w * wg.w;
        #pragma unroll
        for (int m = 1; m <= 16; m <<= 1) d += __shfl_xor(d, m);
        const float g = 1.f / (1.f + expf(-(d + bg)));
        acc.x += g * v.x;
        acc.y += g * v.y;
        acc.z += g * v.z;
        acc.w += g * v.w;
        tacc  += g;
    }

    // cross-group reduction via LDS
    ((float4*)lds_s)[grp * 32 + lane] = acc;
    if (lane == 0) lds_t[grp] = tacc;
    __syncthreads();

    float* pout = part + (size_t)bc * PSTRIDE;
    if (tid < 128) {
        float s = 0.f;
        #pragma unroll
        for (int g2 = 0; g2 < 8; ++g2) s += lds_s[g2 * 128 + tid];
        pout[tid] = s;
    }
    if (tid == 0) {
        float t = 0.f;
        #pragma unroll
        for (int g2 = 0; g2 < 8; ++g2) t += lds_t[g2];
        pout[128] = t;
    }

    // ---- arrival protocol: last block per b finalizes ----
    __threadfence();                         // release: partials visible device-wide
    __syncthreads();                         // all threads' writes+fences done
    if (tid == 0) is_last = (atomicAdd(&cnt[b], 1) == S_CHUNKS - 1);
    __syncthreads();
    if (!is_last) return;
    __threadfence();                         // acquire: invalidate stale cache lines

    // ---- finalize graph b (256 threads alive, 128 used for compute) ----
    const float* pb = part + (size_t)b * S_CHUNKS * PSTRIDE;
    if (tid < 128) {
        float s = 0.f;
        #pragma unroll
        for (int cc = 0; cc < S_CHUNKS; ++cc) s += pb[cc * PSTRIDE + tid];
        lds_s[tid] = s;
    }
    float t = 0.f;
    #pragma unroll
    for (int cc = 0; cc < S_CHUNKS; ++cc) t += pb[cc * PSTRIDE + 128];  // broadcast
    __syncthreads();

    float hg = 0.f;
    if (tid < 128) {
        hg = t * b_f[tid];
        const float4* wrow = (const float4*)(W_f + (size_t)tid * DD);
        const float4* sv   = (const float4*)lds_s;
        #pragma unroll 8
        for (int k = 0; k < 32; ++k) {
            const float4 w  = wrow[k];
            const float4 sk = sv[k];         // LDS broadcast, conflict-free
            hg += w.x * sk.x + w.y * sk.y + w.z * sk.z + w.w * sk.w;
        }
        float sq = hg * hg;
        sq += __shfl_xor(sq, 1);
        sq += __shfl_xor(sq, 2);
        sq += __shfl_xor(sq, 4);
        sq += __shfl_xor(sq, 8);
        sq += __shfl_xor(sq, 16);
        sq += __shfl_xor(sq, 32);
        if ((tid & 63) == 0) red[tid >> 6] = sq;
    }
    __syncthreads();
    if (tid < 128) {
        const float norm = sqrtf(red[0] + red[1]);
        out[(size_t)b * DD + tid] = hg / fmaxf(norm, 1e-12f);
    }
}

extern "C" void kernel_launch(void* const* d_in, const int* in_sizes, int n_in,
                              void* d_out, int out_size, void* d_ws, size_t ws_size,
                              hipStream_t stream) {
    const float* h   = (const float*)d_in[0];
    const int*   ns  = (const int*)  d_in[1];
    const float* W_f = (const float*)d_in[2];
    const float* b_f = (const float*)d_in[3];
    const float* W_g = (const float*)d_in[4];
    const float* b_g = (const float*)d_in[5];
    float* out  = (float*)d_out;

    float* part = (float*)d_ws;                              // 2048*132 floats ≈ 1.08 MB
    int*   cnt  = (int*)(part + (size_t)BB * S_CHUNKS * PSTRIDE);  // 512 ints

    hipMemsetAsync(cnt, 0, BB * sizeof(int), stream);        // zero arrival counters
    k_fused<<<BB * S_CHUNKS, 256, 0, stream>>>(h, ns, W_g, b_g, W_f, b_f, part, cnt, out);
}

// Round 5
// 24.762 us; speedup vs baseline: 12.4730x; 12.4730x over previous
//
#include <hip/hip_runtime.h>
#include <math.h>

#define BB 512
#define NN 512
#define DD 128

// One block per graph b, 512 threads = 16 row-groups x 32 lanes. Zero
// inter-block communication (no fences/atomics — R4's device-scope
// __threadfence cost 400+ us). Phase 1: stream ns[b] rows, per-row gate +
// weighted accumulate. Phase 2 (same block): reduce groups in LDS, GEMV
// with W_f, L2-normalize, store.
__global__ __launch_bounds__(512) void k_graph(
    const float* __restrict__ h,
    const int*   __restrict__ ns,
    const float* __restrict__ W_g,
    const float* __restrict__ b_g,
    const float* __restrict__ W_f,
    const float* __restrict__ b_f,
    float*       __restrict__ out)
{
    const int b    = blockIdx.x;
    const int tid  = threadIdx.x;
    const int grp  = tid >> 5;       // 0..15
    const int lane = tid & 31;

    const int end = ns[b];           // 1..512 valid rows

    __shared__ float lds_s[16 * 128];
    __shared__ float lds_t[16];
    __shared__ float red[2];

    const float4 wg = ((const float4*)W_g)[lane];
    const float  bg = b_g[0];
    const float4* hb = (const float4*)(h + (size_t)b * NN * DD);  // row r -> hb[r*32+lane]

    float4 acc  = make_float4(0.f, 0.f, 0.f, 0.f);
    float  tacc = 0.f;

    int n = grp;
    for (; n + 48 < end; n += 64) {          // 4 rows in flight per group
        const float4 v0 = hb[(size_t)(n     ) * 32 + lane];
        const float4 v1 = hb[(size_t)(n + 16) * 32 + lane];
        const float4 v2 = hb[(size_t)(n + 32) * 32 + lane];
        const float4 v3 = hb[(size_t)(n + 48) * 32 + lane];

        float d0 = v0.x * wg.x + v0.y * wg.y + v0.z * wg.z + v0.w * wg.w;
        float d1 = v1.x * wg.x + v1.y * wg.y + v1.z * wg.z + v1.w * wg.w;
        float d2 = v2.x * wg.x + v2.y * wg.y + v2.z * wg.z + v2.w * wg.w;
        float d3 = v3.x * wg.x + v3.y * wg.y + v3.z * wg.z + v3.w * wg.w;
        #pragma unroll
        for (int m = 1; m <= 16; m <<= 1) {
            d0 += __shfl_xor(d0, m);
            d1 += __shfl_xor(d1, m);
            d2 += __shfl_xor(d2, m);
            d3 += __shfl_xor(d3, m);
        }
        const float g0 = 1.f / (1.f + expf(-(d0 + bg)));
        const float g1 = 1.f / (1.f + expf(-(d1 + bg)));
        const float g2 = 1.f / (1.f + expf(-(d2 + bg)));
        const float g3 = 1.f / (1.f + expf(-(d3 + bg)));

        acc.x += g0 * v0.x + g1 * v1.x + g2 * v2.x + g3 * v3.x;
        acc.y += g0 * v0.y + g1 * v1.y + g2 * v2.y + g3 * v3.y;
        acc.z += g0 * v0.z + g1 * v1.z + g2 * v2.z + g3 * v3.z;
        acc.w += g0 * v0.w + g1 * v1.w + g2 * v2.w + g3 * v3.w;
        tacc  += g0 + g1 + g2 + g3;
    }
    for (; n < end; n += 16) {               // remainder rows
        const float4 v = hb[(size_t)n * 32 + lane];
        float d = v.x * wg.x + v.y * wg.y + v.z * wg.z + v.w * wg.w;
        #pragma unroll
        for (int m = 1; m <= 16; m <<= 1) d += __shfl_xor(d, m);
        const float g = 1.f / (1.f + expf(-(d + bg)));
        acc.x += g * v.x;
        acc.y += g * v.y;
        acc.z += g * v.z;
        acc.w += g * v.w;
        tacc  += g;
    }

    // cross-group reduction via LDS
    ((float4*)lds_s)[grp * 32 + lane] = acc;
    if (lane == 0) lds_t[grp] = tacc;
    __syncthreads();

    // ---- finalize within the block ----
    float s = 0.f, t = 0.f;
    if (tid < 128) {
        #pragma unroll
        for (int g2 = 0; g2 < 16; ++g2) s += lds_s[g2 * 128 + tid];  // per-lane bank, 2/bank: free
        #pragma unroll
        for (int g2 = 0; g2 < 16; ++g2) t += lds_t[g2];              // broadcast
    }
    __syncthreads();                          // all reads of lds_s done before overwrite
    if (tid < 128) lds_s[tid] = s;            // compact s into first 128 slots
    __syncthreads();                          // s visible to waves 0-1

    float hg = 0.f;
    if (tid < 128) {
        hg = t * b_f[tid];
        const float4* wrow = (const float4*)(W_f + (size_t)tid * DD);
        const float4* sv   = (const float4*)lds_s;
        #pragma unroll 8
        for (int k = 0; k < 32; ++k) {
            const float4 w  = wrow[k];
            const float4 sk = sv[k];          // LDS broadcast, conflict-free
            hg += w.x * sk.x + w.y * sk.y + w.z * sk.z + w.w * sk.w;
        }
        float sq = hg * hg;
        sq += __shfl_xor(sq, 1);
        sq += __shfl_xor(sq, 2);
        sq += __shfl_xor(sq, 4);
        sq += __shfl_xor(sq, 8);
        sq += __shfl_xor(sq, 16);
        sq += __shfl_xor(sq, 32);
        if ((tid & 63) == 0) red[tid >> 6] = sq;
    }
    __syncthreads();
    if (tid < 128) {
        const float norm = sqrtf(red[0] + red[1]);
        out[(size_t)b * DD + tid] = hg / fmaxf(norm, 1e-12f);
    }
}

extern "C" void kernel_launch(void* const* d_in, const int* in_sizes, int n_in,
                              void* d_out, int out_size, void* d_ws, size_t ws_size,
                              hipStream_t stream) {
    const float* h   = (const float*)d_in[0];
    const int*   ns  = (const int*)  d_in[1];
    const float* W_f = (const float*)d_in[2];
    const float* b_f = (const float*)d_in[3];
    const float* W_g = (const float*)d_in[4];
    const float* b_g = (const float*)d_in[5];
    float* out = (float*)d_out;

    k_graph<<<BB, 512, 0, stream>>>(h, ns, W_g, b_g, W_f, b_f, out);
}